// Round 1
// baseline (119.780 us; speedup 1.0000x reference)
//
#include <hip/hip_runtime.h>
#include <hip/hip_bf16.h>
#include <math.h>

// Problem constants (from reference setup_inputs):
// B=16, S=T=512, D=512, R=8.  All inputs/outputs float32.
#define B 16
#define Sn 512
#define Tn 512
#define Dn 512
#define Rn 8
#define NEG_BIG (-1e10f)

// ---------------------------------------------------------------------------
// Kernel A: row-l2-normalize w [R=8, D=512]; also emit g[r] = ||w_r||^2 after
// normalization (≈1, kept for exactness vs reference).
// 1 block, 512 threads = 8 waves; wave r handles row r.
__global__ __launch_bounds__(512) void norm_w_kernel(
    const float* __restrict__ w_in, float* __restrict__ w_out,
    float* __restrict__ g_out) {
  int lane = threadIdx.x & 63;
  int r = threadIdx.x >> 6;
  float x[8];
  float ss = 0.f;
#pragma unroll
  for (int j = 0; j < 8; ++j) {
    x[j] = w_in[r * Dn + 64 * j + lane];
    ss += x[j] * x[j];
  }
#pragma unroll
  for (int off = 32; off; off >>= 1) ss += __shfl_xor(ss, off, 64);
  float n = sqrtf(ss);
  float inv = 1.0f / fmaxf(n, 1e-12f);
#pragma unroll
  for (int j = 0; j < 8; ++j) w_out[r * Dn + 64 * j + lane] = x[j] * inv;
  if (lane == 0) g_out[r] = ss * inv * inv;
}

// ---------------------------------------------------------------------------
// Kernel B: wt[b,r,n] = sum_d emb[b,n,d] * w[r,d].  One wave per (b,n) row.
// emb rows read as 2x float4 per lane (coalesced 1KB/instr); w staged in LDS
// as float4 (stride-16B b128 reads, conflict-free).
__global__ __launch_bounds__(256) void proj_kernel(
    const float* __restrict__ emb, const float* __restrict__ w,
    float* __restrict__ wt) {
  __shared__ float4 w4[Rn * 128];  // 16 KB
  const float4* wg = (const float4*)w;
  for (int i = threadIdx.x; i < Rn * 128; i += 256) w4[i] = wg[i];
  __syncthreads();

  int wid = threadIdx.x >> 6, lane = threadIdx.x & 63;
  int row = blockIdx.x * 4 + wid;  // 0..B*N-1  (N=512)
  const float4* e4 = (const float4*)(emb + (size_t)row * Dn);
  float4 xa = e4[lane];
  float4 xb = e4[lane + 64];

  float p[8];
#pragma unroll
  for (int r = 0; r < 8; ++r) {
    float4 wa = w4[r * 128 + lane];
    float4 wb = w4[r * 128 + lane + 64];
    p[r] = xa.x * wa.x + xa.y * wa.y + xa.z * wa.z + xa.w * wa.w +
           xb.x * wb.x + xb.y * wb.y + xb.z * wb.z + xb.w * wb.w;
  }
#pragma unroll
  for (int off = 32; off; off >>= 1) {
#pragma unroll
    for (int r = 0; r < 8; ++r) p[r] += __shfl_xor(p[r], off, 64);
  }
  if (lane == 0) {
    int b = row >> 9, n = row & 511;
#pragma unroll
    for (int r = 0; r < 8; ++r) wt[(((size_t)b * Rn + r) << 9) + n] = p[r];
  }
}

// ---------------------------------------------------------------------------
// Kernel C: per (b,r,s) row: softmax over t of
//   score[t] = g_r*src_wt*tar_wt[t] + (1 - src_mask[b,s]*tar_mask[b,t])*NEG_BIG
// then c[b,r,s] = sum_t softmax[t] * tar_wt[t].
// Block = 4 waves, handles one (b,r) pair and a 32-row s-chunk (8 rows/wave).
__global__ __launch_bounds__(256) void softmax_kernel(
    const float* __restrict__ src_wt, const float* __restrict__ tar_wt,
    const float* __restrict__ src_mask, const float* __restrict__ tar_mask,
    const float* __restrict__ g, float* __restrict__ cbuf) {
  int pair = blockIdx.x >> 4;   // 0..B*R-1
  int chunk = blockIdx.x & 15;  // 0..15 (s-chunks of 32)
  int b = pair >> 3, r = pair & 7;

  __shared__ float tw_s[Tn], tm_s[Tn];
  for (int i = threadIdx.x; i < Tn; i += 256) {
    tw_s[i] = tar_wt[((size_t)pair << 9) + i];
    tm_s[i] = tar_mask[((size_t)b << 9) + i];
  }
  __syncthreads();

  int wid = threadIdx.x >> 6, lane = threadIdx.x & 63;
  float gr = g[r];
  float tw[8], tmn[8];
#pragma unroll
  for (int j = 0; j < 8; ++j) {
    tw[j] = tw_s[lane + 64 * j];   // conflict-free (stride-4B)
    tmn[j] = tm_s[lane + 64 * j];
  }

  for (int i = 0; i < 8; ++i) {
    int s = chunk * 32 + wid * 8 + i;
    float sw = src_wt[((size_t)pair << 9) + s];   // wave-broadcast load
    float sm = src_mask[((size_t)b << 9) + s];
    float a = gr * sw;
    float sc[8];
    float m = -INFINITY;
#pragma unroll
    for (int j = 0; j < 8; ++j) {
      sc[j] = a * tw[j] + (1.0f - sm * tmn[j]) * NEG_BIG;
      m = fmaxf(m, sc[j]);
    }
#pragma unroll
    for (int off = 32; off; off >>= 1) m = fmaxf(m, __shfl_xor(m, off, 64));
    float ps = 0.f, wsum = 0.f;
#pragma unroll
    for (int j = 0; j < 8; ++j) {
      float p = __expf(sc[j] - m);
      ps += p;
      wsum += p * tw[j];
    }
#pragma unroll
    for (int off = 32; off; off >>= 1) {
      ps += __shfl_xor(ps, off, 64);
      wsum += __shfl_xor(wsum, off, 64);
    }
    if (lane == 0) cbuf[((size_t)pair << 9) + s] = wsum / ps;
  }
}

// ---------------------------------------------------------------------------
// Kernel D: out[b,s,:] = sum_r c[b,r,s] * w[r,:].  One wave per (b,s) row;
// w staged in LDS as float4; output written as 2 coalesced float4/lane.
__global__ __launch_bounds__(256) void out_kernel(
    const float* __restrict__ cbuf, const float* __restrict__ w,
    float* __restrict__ out) {
  __shared__ float4 w4[Rn * 128];  // 16 KB
  const float4* wg = (const float4*)w;
  for (int i = threadIdx.x; i < Rn * 128; i += 256) w4[i] = wg[i];
  __syncthreads();

  int wid = threadIdx.x >> 6, lane = threadIdx.x & 63;
  int row = blockIdx.x * 4 + wid;  // b*S + s
  int b = row >> 9, s = row & 511;

  float cv[8];
#pragma unroll
  for (int r = 0; r < 8; ++r)
    cv[r] = cbuf[(((size_t)b * Rn + r) << 9) + s];  // wave-broadcast loads

  float4 a0 = {0, 0, 0, 0}, a1 = {0, 0, 0, 0};
#pragma unroll
  for (int r = 0; r < 8; ++r) {
    float4 wa = w4[r * 128 + lane];
    float4 wb = w4[r * 128 + lane + 64];
    a0.x += cv[r] * wa.x; a0.y += cv[r] * wa.y;
    a0.z += cv[r] * wa.z; a0.w += cv[r] * wa.w;
    a1.x += cv[r] * wb.x; a1.y += cv[r] * wb.y;
    a1.z += cv[r] * wb.z; a1.w += cv[r] * wb.w;
  }
  float4* o4 = (float4*)(out + (size_t)row * Dn);
  o4[lane] = a0;
  o4[lane + 64] = a1;
}

// ---------------------------------------------------------------------------
extern "C" void kernel_launch(void* const* d_in, const int* in_sizes, int n_in,
                              void* d_out, int out_size, void* d_ws,
                              size_t ws_size, hipStream_t stream) {
  const float* src_emb = (const float*)d_in[0];   // [B,S,D]
  const float* tar_emb = (const float*)d_in[1];   // [B,T,D]
  const float* src_mask = (const float*)d_in[2];  // [B,S]
  const float* tar_mask = (const float*)d_in[3];  // [B,T]
  const float* w_in = (const float*)d_in[4];      // [R,D]
  float* out = (float*)d_out;                     // [B,S,D]

  // Workspace layout (floats), all 16B-aligned:
  float* ws = (float*)d_ws;
  float* w_norm = ws;            // 4096
  float* g = ws + 4096;          // 8 (+pad to 4112)
  float* src_wt = ws + 4112;     // 65536  [B,R,S]
  float* tar_wt = ws + 69648;    // 65536  [B,R,T]
  float* cbuf = ws + 135184;     // 65536  [B,R,S]
  // total ~803 KB << ws_size

  norm_w_kernel<<<1, 512, 0, stream>>>(w_in, w_norm, g);
  proj_kernel<<<(B * Sn) / 4, 256, 0, stream>>>(src_emb, w_norm, src_wt);
  proj_kernel<<<(B * Tn) / 4, 256, 0, stream>>>(tar_emb, w_norm, tar_wt);
  softmax_kernel<<<B * Rn * (Sn / 32), 256, 0, stream>>>(
      src_wt, tar_wt, src_mask, tar_mask, g, cbuf);
  out_kernel<<<(B * Sn) / 4, 256, 0, stream>>>(cbuf, w_norm, out);
}

// Round 3
// 116.831 us; speedup vs baseline: 1.0252x; 1.0252x over previous
//
#include <hip/hip_runtime.h>
#include <hip/hip_bf16.h>
#include <math.h>

// B=16, S=T=512, D=512, R=8.  All inputs/outputs float32.
#define B 16
#define Sn 512
#define Tn 512
#define Dn 512
#define Rn 8
#define NEG_BIG (-1e10f)

__device__ __forceinline__ float wred_sum(float v) {
#pragma unroll
  for (int off = 32; off; off >>= 1) v += __shfl_xor(v, off, 64);
  return v;
}
__device__ __forceinline__ float wred_max(float v) {
#pragma unroll
  for (int off = 32; off; off >>= 1) v = fmaxf(v, __shfl_xor(v, off, 64));
  return v;
}

// Per-block: load w [8,512] (16 KB, L2-hot), l2-normalize rows into LDS w4n,
// write gs[r] = ||w_r||^2 after normalization (≈1, kept for exactness).
// block=256: wave w handles rows 2w and 2w+1.
__device__ __forceinline__ void stage_norm_w(const float* __restrict__ w,
                                             float4* w4n, float* gs) {
  const float4* wg = (const float4*)w;
  int wid = threadIdx.x >> 6, lane = threadIdx.x & 63;
  int base = wid * 256;
  float4 g0 = wg[base + lane];
  float4 g1 = wg[base + 64 + lane];
  float4 g2 = wg[base + 128 + lane];
  float4 g3 = wg[base + 192 + lane];
  float ss0 = g0.x * g0.x + g0.y * g0.y + g0.z * g0.z + g0.w * g0.w +
              g1.x * g1.x + g1.y * g1.y + g1.z * g1.z + g1.w * g1.w;
  float ss1 = g2.x * g2.x + g2.y * g2.y + g2.z * g2.z + g2.w * g2.w +
              g3.x * g3.x + g3.y * g3.y + g3.z * g3.z + g3.w * g3.w;
  ss0 = wred_sum(ss0);
  ss1 = wred_sum(ss1);
  float inv0 = 1.0f / fmaxf(sqrtf(ss0), 1e-12f);
  float inv1 = 1.0f / fmaxf(sqrtf(ss1), 1e-12f);
  float4 o;
  o.x = g0.x * inv0; o.y = g0.y * inv0; o.z = g0.z * inv0; o.w = g0.w * inv0;
  w4n[base + lane] = o;
  o.x = g1.x * inv0; o.y = g1.y * inv0; o.z = g1.z * inv0; o.w = g1.w * inv0;
  w4n[base + 64 + lane] = o;
  o.x = g2.x * inv1; o.y = g2.y * inv1; o.z = g2.z * inv1; o.w = g2.w * inv1;
  w4n[base + 128 + lane] = o;
  o.x = g3.x * inv1; o.y = g3.y * inv1; o.z = g3.z * inv1; o.w = g3.w * inv1;
  w4n[base + 192 + lane] = o;
  if (lane == 0) {
    gs[2 * wid] = ss0 * inv0 * inv0;
    gs[2 * wid + 1] = ss1 * inv1 * inv1;
  }
}

// ---------------------------------------------------------------------------
// Kernel 1: wt[b,r,n] = sum_d emb[b,n,d] * w_norm[r,d] for BOTH src and tar.
// Grid 4096: first 2048 blocks -> src, rest -> tar. One wave per (b,n) row.
__global__ __launch_bounds__(256) void proj_kernel(
    const float* __restrict__ src_emb, const float* __restrict__ tar_emb,
    const float* __restrict__ w, float* __restrict__ src_wt,
    float* __restrict__ tar_wt) {
  __shared__ float4 w4n[Rn * 128];  // 16 KB
  __shared__ float gs[Rn];
  stage_norm_w(w, w4n, gs);
  __syncthreads();

  bool is_src = blockIdx.x < 2048;
  const float* emb = is_src ? src_emb : tar_emb;
  float* wt = is_src ? src_wt : tar_wt;
  int bb = is_src ? blockIdx.x : blockIdx.x - 2048;

  int wid = threadIdx.x >> 6, lane = threadIdx.x & 63;
  int row = bb * 4 + wid;  // b*512 + n
  const float4* e4 = (const float4*)(emb + (size_t)row * Dn);
  float4 xa = e4[lane];
  float4 xb = e4[lane + 64];

  float p[8];
#pragma unroll
  for (int r = 0; r < 8; ++r) {
    float4 wa = w4n[r * 128 + lane];
    float4 wb = w4n[r * 128 + 64 + lane];
    p[r] = xa.x * wa.x + xa.y * wa.y + xa.z * wa.z + xa.w * wa.w +
           xb.x * wb.x + xb.y * wb.y + xb.z * wb.z + xb.w * wb.w;
  }
#pragma unroll
  for (int off = 32; off; off >>= 1) {
#pragma unroll
    for (int r = 0; r < 8; ++r) p[r] += __shfl_xor(p[r], off, 64);
  }
  if (lane == 0) {
    int b = row >> 9, n = row & 511;
#pragma unroll
    for (int r = 0; r < 8; ++r) wt[(((size_t)b * Rn + r) << 9) + n] = p[r];
  }
}

// ---------------------------------------------------------------------------
// Kernel 2: fused softmax + output expansion.
//   c[b,r,s] = sum_t softmax_t(g_r*sw*tw[t] + maskterm) * tw[t]
//   out[b,s,:] = sum_r c[b,r,s] * w_norm[r,:]
// Grid = B*64 blocks; block = 4 waves; block handles (b, 8 s-rows); each wave
// does 2 s-rows with tar_wt[b,:,:] held entirely in registers (16 float4).
__global__ __launch_bounds__(256) void fused_kernel(
    const float* __restrict__ src_wt, const float* __restrict__ tar_wt,
    const float* __restrict__ src_mask, const float* __restrict__ tar_mask,
    const float* __restrict__ w, float* __restrict__ out) {
  __shared__ float4 w4n[Rn * 128];  // 16 KB
  __shared__ float gs[Rn];
  __shared__ float sw_s[Rn][8];  // src_wt[b, r, s0..s0+7]
  __shared__ float sm_s[8];

  int b = blockIdx.x >> 6;
  int s0 = (blockIdx.x & 63) * 8;

  stage_norm_w(w, w4n, gs);
  if (threadIdx.x < 64) {
    int r = threadIdx.x >> 3, si = threadIdx.x & 7;
    sw_s[r][si] = src_wt[(((size_t)b * Rn + r) << 9) + s0 + si];
    if (r == 0) sm_s[si] = src_mask[((size_t)b << 9) + s0 + si];
  }
  __syncthreads();

  int wid = threadIdx.x >> 6, lane = threadIdx.x & 63;

  // tar_wt[b] rows in registers: tw[r][0..1] = 8 t-values per lane.
  const float4* twb = (const float4*)(tar_wt + ((size_t)b << 12));
  float4 tw[8][2];
#pragma unroll
  for (int r = 0; r < 8; ++r) {
    tw[r][0] = twb[r * 128 + lane];
    tw[r][1] = twb[r * 128 + 64 + lane];
  }
  const float4* tmb = (const float4*)(tar_mask + ((size_t)b << 9));
  float4 tm0 = tmb[lane], tm1 = tmb[lane + 64];
  float gr[8];
#pragma unroll
  for (int r = 0; r < 8; ++r) gr[r] = gs[r];

#pragma unroll
  for (int it = 0; it < 2; ++it) {
    int sl = wid * 2 + it;  // 0..7
    int s = s0 + sl;
    float sm = sm_s[sl];
    float mk[8];
    mk[0] = (1.0f - sm * tm0.x) * NEG_BIG;
    mk[1] = (1.0f - sm * tm0.y) * NEG_BIG;
    mk[2] = (1.0f - sm * tm0.z) * NEG_BIG;
    mk[3] = (1.0f - sm * tm0.w) * NEG_BIG;
    mk[4] = (1.0f - sm * tm1.x) * NEG_BIG;
    mk[5] = (1.0f - sm * tm1.y) * NEG_BIG;
    mk[6] = (1.0f - sm * tm1.z) * NEG_BIG;
    mk[7] = (1.0f - sm * tm1.w) * NEG_BIG;

    float cacc[8];
#pragma unroll
    for (int r = 0; r < 8; ++r) {
      float a = gr[r] * sw_s[r][sl];
      float twv[8] = {tw[r][0].x, tw[r][0].y, tw[r][0].z, tw[r][0].w,
                      tw[r][1].x, tw[r][1].y, tw[r][1].z, tw[r][1].w};
      float sc[8];
      float m = -INFINITY;
#pragma unroll
      for (int k = 0; k < 8; ++k) {
        sc[k] = a * twv[k] + mk[k];
        m = fmaxf(m, sc[k]);
      }
      m = wred_max(m);
      float ps = 0.f, wsum = 0.f;
#pragma unroll
      for (int k = 0; k < 8; ++k) {
        float p = __expf(sc[k] - m);
        ps += p;
        wsum += p * twv[k];
      }
      ps = wred_sum(ps);
      wsum = wred_sum(wsum);
      cacc[r] = wsum / ps;
    }

    float4 o0 = {0, 0, 0, 0}, o1 = {0, 0, 0, 0};
#pragma unroll
    for (int r = 0; r < 8; ++r) {
      float4 wa = w4n[r * 128 + lane];
      float4 wb = w4n[r * 128 + 64 + lane];
      o0.x += cacc[r] * wa.x; o0.y += cacc[r] * wa.y;
      o0.z += cacc[r] * wa.z; o0.w += cacc[r] * wa.w;
      o1.x += cacc[r] * wb.x; o1.y += cacc[r] * wb.y;
      o1.z += cacc[r] * wb.z; o1.w += cacc[r] * wb.w;
    }
    float4* dst = (float4*)(out + (((size_t)b << 9) + s) * Dn);
    dst[lane] = o0;
    dst[lane + 64] = o1;
  }
}

// ---------------------------------------------------------------------------
extern "C" void kernel_launch(void* const* d_in, const int* in_sizes, int n_in,
                              void* d_out, int out_size, void* d_ws,
                              size_t ws_size, hipStream_t stream) {
  const float* src_emb = (const float*)d_in[0];   // [B,S,D]
  const float* tar_emb = (const float*)d_in[1];   // [B,T,D]
  const float* src_mask = (const float*)d_in[2];  // [B,S]
  const float* tar_mask = (const float*)d_in[3];  // [B,T]
  const float* w_in = (const float*)d_in[4];      // [R,D]
  float* out = (float*)d_out;                     // [B,S,D]

  float* ws = (float*)d_ws;
  float* src_wt = ws;           // 65536  [B,R,S]
  float* tar_wt = ws + 65536;   // 65536  [B,R,T]

  proj_kernel<<<4096, 256, 0, stream>>>(src_emb, tar_emb, w_in, src_wt, tar_wt);
  fused_kernel<<<B * 64, 256, 0, stream>>>(src_wt, tar_wt, src_mask, tar_mask,
                                           w_in, out);
}

// Round 4
// 102.318 us; speedup vs baseline: 1.1707x; 1.1418x over previous
//
#include <hip/hip_runtime.h>
#include <hip/hip_bf16.h>
#include <math.h>

// B=16, S=T=512, D=512, R=8.  All float32.
#define B 16
#define Sn 512
#define Tn 512
#define Dn 512
#define Rn 8
#define NEG_BIG (-1e10f)
#define L2E 1.4426950408889634f

__device__ __forceinline__ float dot4(float4 a, float4 b) {
  return a.x * b.x + a.y * b.y + a.z * b.z + a.w * b.w;
}

// Sum p[0..7] across 64 lanes with 10 shuffles (vs 48 for full butterfly).
// Returns, in every lane, the total sum of p[r] for r = lane&7.
__device__ __forceinline__ float fold_reduce8(const float* p, int lane) {
  bool b0 = lane & 1;
  float q[4];
#pragma unroll
  for (int j = 0; j < 4; ++j) {
    float s = b0 ? p[2 * j] : p[2 * j + 1];
    float rv = __shfl_xor(s, 1, 64);
    q[j] = (b0 ? p[2 * j + 1] : p[2 * j]) + rv;
  }
  bool b1 = lane & 2;
  float u[2];
#pragma unroll
  for (int j = 0; j < 2; ++j) {
    float s = b1 ? q[2 * j] : q[2 * j + 1];
    float rv = __shfl_xor(s, 2, 64);
    u[j] = (b1 ? q[2 * j + 1] : q[2 * j]) + rv;
  }
  bool b2 = lane & 4;
  float s = b2 ? u[0] : u[1];
  float rv = __shfl_xor(s, 4, 64);
  float v = (b2 ? u[1] : u[0]) + rv;
  v += __shfl_xor(v, 8, 64);
  v += __shfl_xor(v, 16, 64);
  v += __shfl_xor(v, 32, 64);
  return v;
}

// Load w[8][512] into registers (lane's d-slice: d4=lane and d4=64+lane),
// l2-normalize rows in-register; g[r] = ||w_r||^2 post-normalize (≈1).
__device__ __forceinline__ void load_norm_w(const float* __restrict__ w,
                                            int lane, float4* wa, float4* wb,
                                            float* g) {
  const float4* wg = (const float4*)w;
  float ss[8];
#pragma unroll
  for (int r = 0; r < 8; ++r) {
    wa[r] = wg[r * 128 + lane];
    wb[r] = wg[r * 128 + 64 + lane];
    ss[r] = dot4(wa[r], wa[r]) + dot4(wb[r], wb[r]);
  }
#pragma unroll
  for (int off = 32; off; off >>= 1) {
#pragma unroll
    for (int r = 0; r < 8; ++r) ss[r] += __shfl_xor(ss[r], off, 64);
  }
#pragma unroll
  for (int r = 0; r < 8; ++r) {
    float iv = 1.0f / fmaxf(sqrtf(ss[r]), 1e-12f);
    wa[r].x *= iv; wa[r].y *= iv; wa[r].z *= iv; wa[r].w *= iv;
    wb[r].x *= iv; wb[r].y *= iv; wb[r].z *= iv; wb[r].w *= iv;
    g[r] = ss[r] * iv * iv;
  }
}

// ---------------------------------------------------------------------------
// Kernel 1: wt[row][r] = <emb[row,:], w_norm[r,:]>, layout [b*512+n][8].
// 1024 blocks x 256; wave handles 4 rows; w in registers; no LDS staging.
__global__ __launch_bounds__(256) void proj_kernel(
    const float* __restrict__ src_emb, const float* __restrict__ tar_emb,
    const float* __restrict__ w, float* __restrict__ src_wt,
    float* __restrict__ tar_wt) {
  int lane = threadIdx.x & 63, wid = threadIdx.x >> 6;
  float4 wa[8], wb[8];
  float g[8];
  load_norm_w(w, lane, wa, wb, g);

  int row0 = blockIdx.x * 16 + wid * 4;  // 4 rows per wave
  bool is_src = row0 < B * Sn;
  const float* emb = is_src ? src_emb : tar_emb;
  float* wt = is_src ? src_wt : tar_wt;
  int rb = is_src ? row0 : row0 - B * Sn;

  float v[4];
#pragma unroll
  for (int i = 0; i < 4; ++i) {
    const float4* e4 = (const float4*)(emb + (size_t)(rb + i) * Dn);
    float4 xa = e4[lane];
    float4 xb = e4[64 + lane];
    float p[8];
#pragma unroll
    for (int r = 0; r < 8; ++r) p[r] = dot4(xa, wa[r]) + dot4(xb, wb[r]);
    v[i] = fold_reduce8(p, lane);
  }
  // lanes 0..31 store 4 rows x 8 r = 32 consecutive floats (one coalesced op)
  if (lane < 32) {
    int ri = lane >> 3;
    float val = (ri == 0) ? v[0] : (ri == 1) ? v[1] : (ri == 2) ? v[2] : v[3];
    wt[(size_t)(rb + ri) * 8 + (lane & 7)] = val;
  }
}

// ---------------------------------------------------------------------------
// Kernel 2: fused softmax + output.  512 blocks x 256; block = (b, 16 s-rows).
// Lane owns (s_local, r, t-half); serial t-loop, zero shuffles inside.
// Softmax via safe bound m' = |a|*maxabs(tw) + (1-sm)*NEG (shift-invariant).
__global__ __launch_bounds__(256) void fused_kernel(
    const float* __restrict__ src_wt, const float* __restrict__ tar_wt,
    const float* __restrict__ src_mask, const float* __restrict__ tar_mask,
    const float* __restrict__ w, float* __restrict__ out) {
  __shared__ __align__(16) float tw_lds[Tn * 12];  // stride 12 floats, 24 KB
  __shared__ float tm_lds[Tn];
  __shared__ __align__(16) float cacc_lds[16 * 8];
  __shared__ float mred[4];

  int lane = threadIdx.x & 63, wid = threadIdx.x >> 6;
  int b = blockIdx.x >> 5;
  int s0 = (blockIdx.x & 31) * 16;

  float4 wa[8], wb[8];
  float g[8];
  load_norm_w(w, lane, wa, wb, g);

  // stage tar_wt[b] (16 KB) + tar_mask[b]; track block maxabs(tw)
  const float4* twg = (const float4*)(tar_wt + (size_t)b * Tn * 8);
  float mloc = 0.0f;
#pragma unroll
  for (int k = 0; k < 4; ++k) {
    int idx = k * 256 + threadIdx.x;  // float4 index; t=idx>>1, half=idx&1
    float4 vv = twg[idx];
    int t = idx >> 1, hf = idx & 1;
    *(float4*)&tw_lds[t * 12 + hf * 4] = vv;
    mloc = fmaxf(mloc, fmaxf(fmaxf(fabsf(vv.x), fabsf(vv.y)),
                             fmaxf(fabsf(vv.z), fabsf(vv.w))));
  }
  for (int k = threadIdx.x; k < Tn; k += 256)
    tm_lds[k] = tar_mask[b * Tn + k];
#pragma unroll
  for (int off = 32; off; off >>= 1)
    mloc = fmaxf(mloc, __shfl_xor(mloc, off, 64));
  if (lane == 0) mred[wid] = mloc;
  __syncthreads();
  float M = fmaxf(fmaxf(mred[0], mred[1]), fmaxf(mred[2], mred[3]));

  int r = lane & 7, h = (lane >> 3) & 1, sl4 = lane >> 4;
  int s_local = wid * 4 + sl4;
  int s = s0 + s_local;

  float g_r = (r & 4) ? ((r & 2) ? ((r & 1) ? g[7] : g[6])
                                 : ((r & 1) ? g[5] : g[4]))
                      : ((r & 2) ? ((r & 1) ? g[3] : g[2])
                                 : ((r & 1) ? g[1] : g[0]));
  float sw = src_wt[((size_t)(b * Sn + s)) * 8 + r];
  float sm = src_mask[b * Sn + s];
  float a = g_r * sw;
  // sc2 = L2E*(score - m'),  score = a*tw + (1 - sm*tm)*NEG,
  // m' = |a|*M + (1-sm)*NEG  =>  sc2 = A2*tw + Bm*tm + C2, always <= 0.
  float A2 = a * L2E;
  float Bm = sm * (-NEG_BIG) * L2E;
  float C2 = L2E * (sm * NEG_BIG - fabsf(a) * M);

  float ps = 0.0f, wsum = 0.0f;
  int t0 = h * 256;
#pragma unroll 8
  for (int t = t0; t < t0 + 256; ++t) {
    float tw = tw_lds[t * 12 + r];
    float tm = tm_lds[t];
    float sc = fmaf(A2, tw, fmaf(Bm, tm, C2));
    float p = __builtin_amdgcn_exp2f(sc);
    ps += p;
    wsum = fmaf(p, tw, wsum);
  }
  // merge the two t-halves (same m' => plain adds)
  ps += __shfl_xor(ps, 8, 64);
  wsum += __shfl_xor(wsum, 8, 64);
  if (h == 0) cacc_lds[s_local * 8 + r] = wsum / ps;
  __syncthreads();

  // epilogue: wave writes 4 s-rows; w in registers; coalesced float4 stores
#pragma unroll
  for (int i = 0; i < 4; ++i) {
    int srow = wid * 4 + i;
    float4 c0 = *(const float4*)&cacc_lds[srow * 8];
    float4 c1 = *(const float4*)&cacc_lds[srow * 8 + 4];
    float cc[8] = {c0.x, c0.y, c0.z, c0.w, c1.x, c1.y, c1.z, c1.w};
    float4 o0 = {0, 0, 0, 0}, o1 = {0, 0, 0, 0};
#pragma unroll
    for (int rr = 0; rr < 8; ++rr) {
      o0.x = fmaf(cc[rr], wa[rr].x, o0.x);
      o0.y = fmaf(cc[rr], wa[rr].y, o0.y);
      o0.z = fmaf(cc[rr], wa[rr].z, o0.z);
      o0.w = fmaf(cc[rr], wa[rr].w, o0.w);
      o1.x = fmaf(cc[rr], wb[rr].x, o1.x);
      o1.y = fmaf(cc[rr], wb[rr].y, o1.y);
      o1.z = fmaf(cc[rr], wb[rr].z, o1.z);
      o1.w = fmaf(cc[rr], wb[rr].w, o1.w);
    }
    float4* dst = (float4*)(out + (size_t)(b * Sn + s0 + srow) * Dn);
    dst[lane] = o0;
    dst[64 + lane] = o1;
  }
}

// ---------------------------------------------------------------------------
extern "C" void kernel_launch(void* const* d_in, const int* in_sizes, int n_in,
                              void* d_out, int out_size, void* d_ws,
                              size_t ws_size, hipStream_t stream) {
  const float* src_emb = (const float*)d_in[0];   // [B,S,D]
  const float* tar_emb = (const float*)d_in[1];   // [B,T,D]
  const float* src_mask = (const float*)d_in[2];  // [B,S]
  const float* tar_mask = (const float*)d_in[3];  // [B,T]
  const float* w_in = (const float*)d_in[4];      // [R,D]
  float* out = (float*)d_out;                     // [B,S,D]

  float* ws = (float*)d_ws;
  float* src_wt = ws;            // [B*S][R] = 65536 floats
  float* tar_wt = ws + 65536;    // [B*T][R] = 65536 floats

  proj_kernel<<<(B * (Sn + Tn)) / 16, 256, 0, stream>>>(src_emb, tar_emb, w_in,
                                                        src_wt, tar_wt);
  fused_kernel<<<B * (Sn / 16), 256, 0, stream>>>(src_wt, tar_wt, src_mask,
                                                  tar_mask, w_in, out);
}